// Round 14
// baseline (419.082 us; speedup 1.0000x reference)
//
#include <hip/hip_runtime.h>
#include <hip/hip_bf16.h>
#include <stdint.h>

typedef float f32x4 __attribute__((ext_vector_type(4)));
typedef __bf16 bf16x8 __attribute__((ext_vector_type(8)));
typedef unsigned short ushort8 __attribute__((ext_vector_type(8)));

#define NB 8
#define NS 8192
#define ND 512
#define NM (NB * NS)      // 65536 rows
#define NK 512            // reduction dim

// ---------------- helpers ----------------
__device__ __forceinline__ unsigned short f2bf(float f) {
  unsigned u = __float_as_uint(f);
  u += 0x7FFFu + ((u >> 16) & 1u);
  return (unsigned short)(u >> 16);
}

// packed f32x2 -> bf16x2 (RNE)
__device__ __forceinline__ uint32_t cvtpk(float lo, float hi) {
  uint32_t r;
  asm("v_cvt_pk_bf16_f32 %0, %1, %2" : "=v"(r) : "v"(lo), "v"(hi));
  return r;
}

__global__ __launch_bounds__(256) void cvt_bf16(const float* __restrict__ src,
                                                unsigned short* __restrict__ dst,
                                                int n8) {
  int i = blockIdx.x * 256 + threadIdx.x;
  if (i >= n8) return;
  const float4* s = reinterpret_cast<const float4*>(src + (size_t)i * 8);
  float4 v0 = s[0], v1 = s[1];
  ushort8 o;
  o[0] = f2bf(v0.x); o[1] = f2bf(v0.y); o[2] = f2bf(v0.z); o[3] = f2bf(v0.w);
  o[4] = f2bf(v1.x); o[5] = f2bf(v1.y); o[6] = f2bf(v1.z); o[7] = f2bf(v1.w);
  *reinterpret_cast<ushort8*>(dst + (size_t)i * 8) = o;
}

// ---------------- 128x128 flat GEMM: no LDS, no barriers in the K-loop --------
// Block: 128 seq rows (= one scan chunk) x 64 channels (128 W-rows: 64 hidden +
// 64 gate, mixed B-frag mapping so hid/gat pair in-thread). 4 waves, fully
// independent through the K-loop. A fragments loaded straight from f32 x
// (2 x dwordx4 per fragment, cvt_pk at the MFMA boundary); B fragments straight
// from bf16 W (1 x dwordx4) -- W is 1MB, read by every block -> permanently
// L2-hot. One-K-tile register double-buffer; compiler emits counted vmcnt per
// dependency (no drain-to-0, no race surface). T1 XCD grid swizzle keeps each
// mblk's 8 blocks + W on one XCD's L2 (~3MB working set < 4MB).
// Epilogue (identical to R11/R13): in-register a/b, packed pk, fused chunk
// aggregates via ordered kg-shuffles + tiny cross-wr LDS combine.
__global__ __launch_bounds__(256, 2) void gemm_ab(const float* __restrict__ x,
                                                  const unsigned short* __restrict__ wb,
                                                  uint32_t* __restrict__ pk,
                                                  float* __restrict__ aggA,
                                                  float* __restrict__ aggB) {
  __shared__ float aggL[128];     // only LDS: 64 ch x (A,B) epilogue combine

  const int tid = threadIdx.x;
  const int w = tid >> 6;
  const int lane = tid & 63;
  const int wr = w >> 1;          // A-row half
  const int wc = w & 1;           // channel half (32-ch group)
  // T1 bijective XCD swizzle: 4096 = 512 mblk x 8 nblk
  const int orig = blockIdx.x;
  const int wg = (orig & 7) * 512 + (orig >> 3);
  const int mblk = wg >> 3;
  const int nblk = wg & 7;
  const int m0 = mblk * 128;
  const int n0 = nblk * 64;

  const int fr = lane & 15;
  const int kg = lane >> 4;

  // A fragment source: row = wr*64 + i*16 + fr, k base = kg*8 (8 f32 = 2 x 16B)
  const float* pAd[4];
#pragma unroll
  for (int i = 0; i < 4; ++i)
    pAd[i] = x + (size_t)(m0 + wr * 64 + i * 16 + fr) * NK + kg * 8;
  // B fragment source: mixed hidden/gate rows, k base = kg*8 (8 bf16 = 16B)
  const unsigned short* pBd[4];
#pragma unroll
  for (int i = 0; i < 4; ++i) {
    int rowB = ((i < 2) ? (wc * 32 + i * 16) : (64 + wc * 32 + (i - 2) * 16)) + fr;
    int e = (rowB < 64) ? (n0 + rowB) : (448 + n0 + rowB);  // hidden | gate W-rows
    pBd[i] = wb + (size_t)e * NK + kg * 8;
  }

  f32x4 acc[4][4];
#pragma unroll
  for (int i = 0; i < 4; ++i)
#pragma unroll
    for (int j = 0; j < 4; ++j) acc[i][j] = (f32x4)0.0f;

  f32x4 A0r[8], A1r[8];
  uint4 B0r[4], B1r[4];

#define LOADA(DST, KT)                                                        \
  {                                                                           \
    _Pragma("unroll")                                                         \
    for (int i = 0; i < 4; ++i) {                                             \
      DST[2 * i]     = *reinterpret_cast<const f32x4*>(pAd[i] + (KT) * 32);   \
      DST[2 * i + 1] = *reinterpret_cast<const f32x4*>(pAd[i] + (KT) * 32 + 4); \
    }                                                                         \
  }
#define LOADB(DST, KT)                                                        \
  {                                                                           \
    _Pragma("unroll")                                                         \
    for (int i = 0; i < 4; ++i)                                               \
      DST[i] = *reinterpret_cast<const uint4*>(pBd[i] + (KT) * 32);           \
  }
#define COMPUTE(AR, BR)                                                       \
  {                                                                           \
    bf16x8 af[4], bfr[4];                                                     \
    _Pragma("unroll")                                                         \
    for (int i = 0; i < 4; ++i) {                                             \
      uint4 u;                                                                \
      u.x = cvtpk(AR[2 * i][0], AR[2 * i][1]);                                \
      u.y = cvtpk(AR[2 * i][2], AR[2 * i][3]);                                \
      u.z = cvtpk(AR[2 * i + 1][0], AR[2 * i + 1][1]);                        \
      u.w = cvtpk(AR[2 * i + 1][2], AR[2 * i + 1][3]);                        \
      af[i] = *reinterpret_cast<bf16x8*>(&u);                                 \
      bfr[i] = *reinterpret_cast<bf16x8*>(&BR[i]);                            \
    }                                                                         \
    _Pragma("unroll")                                                         \
    for (int i = 0; i < 4; ++i)                                               \
      _Pragma("unroll")                                                       \
      for (int j = 0; j < 4; ++j)                                             \
        acc[i][j] = __builtin_amdgcn_mfma_f32_16x16x32_bf16(af[i], bfr[j],    \
                                                            acc[i][j], 0, 0, 0); \
  }

  LOADA(A0r, 0);
  LOADB(B0r, 0);
#pragma unroll 1
  for (int ktp = 0; ktp < 16; ktp += 2) {
    LOADA(A1r, ktp + 1);
    LOADB(B1r, ktp + 1);
    COMPUTE(A0r, B0r);
    if (ktp < 14) {
      LOADA(A0r, ktp + 2);
      LOADB(B0r, ktp + 2);
    }
    COMPUTE(A1r, B1r);
  }
#undef LOADA
#undef LOADB
#undef COMPUTE

  // ---------------- epilogue: pure-register a/b + chunk aggregates ----------------
  const float LOG2E = 1.44269504f;
  float A64[2], B64[2];
#pragma unroll
  for (int n = 0; n < 2; ++n) {
    const int ch = wc * 32 + n * 16 + fr;
    float Am[4], Bm[4];
#pragma unroll
    for (int m = 0; m < 4; ++m) {
      float As = 1.0f, Bs = 0.0f;
#pragma unroll
      for (int r = 0; r < 4; ++r) {
        float hid = acc[m][n][r];
        float gat = acc[m][n + 2][r];
        float ex1 = __builtin_amdgcn_exp2f(gat * LOG2E);      // exp(gat)
        float a = __builtin_amdgcn_rcpf(1.0f + ex1);          // sigmoid(-gate)
        float z = 1.0f - a;                                   // sigmoid(gate)
        float ex2 = __builtin_amdgcn_exp2f(-hid * LOG2E);     // exp(-hid)
        float gn = __builtin_amdgcn_rcpf(1.0f + ex2);         // sigmoid(hid)
        float g = (hid >= 0.0f) ? (hid + 0.5f) : gn;
        float bb = z * g;
        int row = 64 * wr + 16 * m + 4 * kg + r;
        pk[(size_t)(m0 + row) * ND + n0 + ch] =
            ((uint32_t)f2bf(bb) << 16) | (uint32_t)f2bf(a);
        Bs = fmaf(a, Bs, bb);   // ordered: r ascending
        As *= a;
      }
      Am[m] = As; Bm[m] = Bs;
    }
    // ordered affine all-reduce across kg (4-row segments within 16-row groups)
#pragma unroll
    for (int m = 0; m < 4; ++m) {
      float pA_ = __shfl_xor(Am[m], 16);
      float pB_ = __shfl_xor(Bm[m], 16);
      Bm[m] = (kg & 1) ? fmaf(Am[m], pB_, Bm[m]) : fmaf(pA_, Bm[m], pB_);
      Am[m] *= pA_;
      pA_ = __shfl_xor(Am[m], 32);
      pB_ = __shfl_xor(Bm[m], 32);
      Bm[m] = (kg & 2) ? fmaf(Am[m], pB_, Bm[m]) : fmaf(pA_, Bm[m], pB_);
      Am[m] *= pA_;
    }
    // serial over 16-row groups (ascending)
    float As = Am[0], Bs = Bm[0];
#pragma unroll
    for (int m = 1; m < 4; ++m) { Bs = fmaf(Am[m], Bs, Bm[m]); As *= Am[m]; }
    A64[n] = As; B64[n] = Bs;
  }
  // cross-wr combine (rows 0-63 then 64-127) via 512B LDS
  if (wr == 0 && kg == 0) {
#pragma unroll
    for (int n = 0; n < 2; ++n) {
      int ch = wc * 32 + n * 16 + fr;
      aggL[ch * 2] = A64[n];
      aggL[ch * 2 + 1] = B64[n];
    }
  }
  __syncthreads();
  if (wr == 1 && kg == 0) {
#pragma unroll
    for (int n = 0; n < 2; ++n) {
      int ch = wc * 32 + n * 16 + fr;
      float A0 = aggL[ch * 2], B0 = aggL[ch * 2 + 1];
      size_t o = (size_t)mblk * ND + n0 + ch;    // mblk == global chunk index
      aggA[o] = A0 * A64[n];
      aggB[o] = fmaf(A64[n], B0, B64[n]);
    }
  }
}

// ---------------- scan pass2: prefix + rescan, write out f32 ----------------
__global__ __launch_bounds__(256) void scan_pass2(const uint32_t* __restrict__ pk,
                                                  const float* __restrict__ aggA,
                                                  const float* __restrict__ aggB,
                                                  float* __restrict__ out,
                                                  float* __restrict__ nextp) {
  int bid = blockIdx.x;
  int b = bid >> 6;
  int c = bid & 63;
  int d2 = threadIdx.x;        // channel-pair 0..255

  float h0 = 0.0f, h1 = 0.0f;
  for (int cc = 0; cc < c; ++cc) {
    int o = (b * 64 + cc) * ND + d2 * 2;
    float2 Aa = *reinterpret_cast<const float2*>(&aggA[o]);
    float2 Bb = *reinterpret_cast<const float2*>(&aggB[o]);
    h0 = fmaf(Aa.x, h0, Bb.x);
    h1 = fmaf(Aa.y, h1, Bb.y);
  }
  size_t base = (size_t)(b * NS + c * 128) * ND + d2 * 2;
#pragma unroll 4
  for (int t = 0; t < 128; ++t) {
    size_t idx = base + (size_t)t * ND;
    uint2 v = *reinterpret_cast<const uint2*>(pk + idx);
    float a0 = __uint_as_float(v.x << 16);
    float b0 = __uint_as_float(v.x & 0xffff0000u);
    float a1 = __uint_as_float(v.y << 16);
    float b1 = __uint_as_float(v.y & 0xffff0000u);
    h0 = fmaf(a0, h0, b0);
    h1 = fmaf(a1, h1, b1);
    *reinterpret_cast<float2*>(&out[idx]) = make_float2(h0, h1);
  }
  if (c == 63) {
    *reinterpret_cast<float2*>(&nextp[b * ND + d2 * 2]) = make_float2(h0, h1);
  }
}

// ---------------- launcher ----------------
extern "C" void kernel_launch(void* const* d_in, const int* in_sizes, int n_in,
                              void* d_out, int out_size, void* d_ws, size_t ws_size,
                              hipStream_t stream) {
  const float* x = (const float*)d_in[0];   // (8, 8192, 512) f32
  const float* W = (const float*)d_in[1];   // (1024, 512) f32
  float* out = (float*)d_out;               // 33554432 + 4096 f32

  char* ws = (char*)d_ws;
  uint32_t* pk = (uint32_t*)ws;                                            // 128 MB
  unsigned short* wbf = (unsigned short*)(ws + (size_t)128 * 1024 * 1024); // 1 MB
  float* aggA = (float*)(ws + (size_t)129 * 1024 * 1024);                  // 1 MB
  float* aggB = (float*)(ws + (size_t)130 * 1024 * 1024);                  // 1 MB
  float* nextp = out + (size_t)NM * ND;

  cvt_bf16<<<256, 256, 0, stream>>>(W, wbf, (1024 * NK) / 8);
  gemm_ab<<<4096, 256, 0, stream>>>(x, wbf, pk, aggA, aggB);
  scan_pass2<<<512, 256, 0, stream>>>(pk, aggA, aggB, out, nextp);
}

// Round 15
// 266.218 us; speedup vs baseline: 1.5742x; 1.5742x over previous
//
#include <hip/hip_runtime.h>
#include <hip/hip_bf16.h>
#include <stdint.h>

typedef float f32x4 __attribute__((ext_vector_type(4)));
typedef __bf16 bf16x8 __attribute__((ext_vector_type(8)));
typedef unsigned short ushort8 __attribute__((ext_vector_type(8)));

#define NB 8
#define NS 8192
#define ND 512
#define NM (NB * NS)      // 65536 rows
#define NK 512            // reduction dim

// ---------------- helpers ----------------
__device__ __forceinline__ unsigned short f2bf(float f) {
  unsigned u = __float_as_uint(f);
  u += 0x7FFFu + ((u >> 16) & 1u);
  return (unsigned short)(u >> 16);
}

// packed f32x2 -> bf16x2 (RNE)
__device__ __forceinline__ uint32_t cvtpk(float lo, float hi) {
  uint32_t r;
  asm("v_cvt_pk_bf16_f32 %0, %1, %2" : "=v"(r) : "v"(lo), "v"(hi));
  return r;
}

__global__ __launch_bounds__(256) void cvt_bf16(const float* __restrict__ src,
                                                unsigned short* __restrict__ dst,
                                                int n8) {
  int i = blockIdx.x * 256 + threadIdx.x;
  if (i >= n8) return;
  const float4* s = reinterpret_cast<const float4*>(src + (size_t)i * 8);
  float4 v0 = s[0], v1 = s[1];
  ushort8 o;
  o[0] = f2bf(v0.x); o[1] = f2bf(v0.y); o[2] = f2bf(v0.z); o[3] = f2bf(v0.w);
  o[4] = f2bf(v1.x); o[5] = f2bf(v1.y); o[6] = f2bf(v1.z); o[7] = f2bf(v1.w);
  *reinterpret_cast<ushort8*>(dst + (size_t)i * 8) = o;
}

// ---------------- 128x128 GEMM: A f32-staged (BK=32), B bf16-staged (BK=64) ----
// Block: 128 seq rows (= one scan chunk) x 64 channels (128 W-rows: 64 hidden +
// 64 gate, mixed B-frag mapping so hid/gat pair in-thread). 4 waves.
// A: staged DIRECTLY from f32 x via global_load_lds into 16KB bufs (128 rows x
//    128B = 8 chunks), XOR-swizzled chunk c <- c^(row&7) (R13's proven A path);
//    converted to bf16 with v_cvt_pk_bf16_f32 at the ds_read->MFMA boundary.
// B: R11's PROVEN conflict-free geometry: BK=64 pair-tiles (128 rows x 128B),
//    staged every other kt, read at byte (kk*2+kg*16)^((row&7)<<4).
// Sync: stage-first + one __syncthreads per kt (R11/R13 verified 2-phase).
// 64KB LDS -> 2 blocks/CU. T1 XCD grid swizzle.
// Epilogue (identical to R11/R13): in-register a/b, packed pk, fused chunk aggs.
__global__ __launch_bounds__(256) void gemm_ab(const float* __restrict__ x,
                                               const unsigned short* __restrict__ wb,
                                               uint32_t* __restrict__ pk,
                                               float* __restrict__ aggA,
                                               float* __restrict__ aggB) {
  __shared__ __align__(16) char lds[65536];   // A: 2x16KB @0; B: 2x16KB @32768
  __shared__ float aggL[128];                 // 64 ch x (A,B)

  const int tid = threadIdx.x;
  const int w = tid >> 6;
  const int lane = tid & 63;
  const int wr = w >> 1;          // A-row half
  const int wc = w & 1;           // channel half (32-ch group)
  // T1 bijective XCD swizzle: 4096 = 512 mblk x 8 nblk
  const int orig = blockIdx.x;
  const int wg = (orig & 7) * 512 + (orig >> 3);
  const int mblk = wg >> 3;
  const int nblk = wg & 7;
  const int m0 = mblk * 128;
  const int n0 = nblk * 64;

  const int lrow = lane >> 3;     // 0..7
  // A staging: slot chunk c=lane&7, row&7=lrow -> source chunk = c^lrow (f32 elems)
  const int aSrc = (((lane & 7) ^ lrow) << 2);
  const float* pAf[4];
#pragma unroll
  for (int g = 0; g < 4; ++g) {
    int row = g * 32 + w * 8 + lrow;
    pAf[g] = x + (size_t)(m0 + row) * NK + aSrc;
  }
  // B staging (R11): source col = ((lane&7)^lrow)*8 bf16
  const int bSrc = (((lane & 7) ^ lrow) << 3);
  const unsigned short* pBf[4];
#pragma unroll
  for (int g = 0; g < 4; ++g) {
    int row = g * 32 + w * 8 + lrow;
    int e = (row < 64) ? (n0 + row) : (448 + n0 + row);  // hidden | gate W-rows
    pBf[g] = wb + (size_t)e * NK + bSrc;
  }

  auto stageA = [&](int buf, int kt) {
    char* base = lds + buf * 16384;
    const int ko = kt << 5;                       // 32 f32 per kt
#pragma unroll
    for (int g = 0; g < 4; ++g)
      __builtin_amdgcn_global_load_lds(
          (const __attribute__((address_space(1))) void*)(pAf[g] + ko),
          (__attribute__((address_space(3))) void*)(base + (g * 4 + w) * 1024),
          16, 0, 0);
  };
  auto stageB = [&](int buf, int pair) {
    char* base = lds + 32768 + buf * 16384;
    const int ko = pair << 6;                     // 64 bf16 per pair
#pragma unroll
    for (int g = 0; g < 4; ++g)
      __builtin_amdgcn_global_load_lds(
          (const __attribute__((address_space(1))) void*)(pBf[g] + ko),
          (__attribute__((address_space(3))) void*)(base + (g * 4 + w) * 1024),
          16, 0, 0);
  };

  f32x4 acc[4][4];
#pragma unroll
  for (int i = 0; i < 4; ++i)
#pragma unroll
    for (int j = 0; j < 4; ++j) acc[i][j] = (f32x4)0.0f;

  const int fr = lane & 15;
  const int kg = lane >> 4;

  stageA(0, 0);
  stageB(0, 0);
  __syncthreads();

#pragma unroll 1
  for (int kt = 0; kt < 16; ++kt) {
    const int cur = kt & 1;            // A buffer
    const int bp = (kt >> 1) & 1;      // B buffer (per pair)
    if (kt < 15) stageA(cur ^ 1, kt + 1);
    if ((kt & 1) == 0 && kt < 14) stageB(bp ^ 1, (kt >> 1) + 1);

    const char* ldsA = lds + cur * 16384;
    const char* ldsB = lds + 32768 + bp * 16384;
    bf16x8 af[4], bfr[4];
#pragma unroll
    for (int i = 0; i < 4; ++i) {
      int rowA = wr * 64 + i * 16 + fr;
      int s0 = (((2 * kg) ^ (fr & 7)) << 4);
      int s1 = (((2 * kg + 1) ^ (fr & 7)) << 4);
      f32x4 q0 = *reinterpret_cast<const f32x4*>(ldsA + rowA * 128 + s0);
      f32x4 q1 = *reinterpret_cast<const f32x4*>(ldsA + rowA * 128 + s1);
      uint4 u;
      u.x = cvtpk(q0[0], q0[1]);
      u.y = cvtpk(q0[2], q0[3]);
      u.z = cvtpk(q1[0], q1[1]);
      u.w = cvtpk(q1[2], q1[3]);
      af[i] = *reinterpret_cast<bf16x8*>(&u);
      int rowB = ((i < 2) ? (wc * 32 + i * 16) : (64 + wc * 32 + (i - 2) * 16)) + fr;
      int swzB = ((kt & 1) * 64 + kg * 16) ^ ((rowB & 7) << 4);   // R11 proven
      bfr[i] = *reinterpret_cast<const bf16x8*>(ldsB + rowB * 128 + swzB);
    }
#pragma unroll
    for (int i = 0; i < 4; ++i)
#pragma unroll
      for (int j = 0; j < 4; ++j)
        acc[i][j] = __builtin_amdgcn_mfma_f32_16x16x32_bf16(af[i], bfr[j], acc[i][j], 0, 0, 0);

    __syncthreads();   // one barrier per K-tile (drains staged loads, orders buffers)
  }

  // ---------------- epilogue: pure-register a/b + chunk aggregates ----------------
  const float LOG2E = 1.44269504f;
  float A64[2], B64[2];
#pragma unroll
  for (int n = 0; n < 2; ++n) {
    const int ch = wc * 32 + n * 16 + fr;
    float Am[4], Bm[4];
#pragma unroll
    for (int m = 0; m < 4; ++m) {
      float As = 1.0f, Bs = 0.0f;
#pragma unroll
      for (int r = 0; r < 4; ++r) {
        float hid = acc[m][n][r];
        float gat = acc[m][n + 2][r];
        float ex1 = __builtin_amdgcn_exp2f(gat * LOG2E);      // exp(gat)
        float a = __builtin_amdgcn_rcpf(1.0f + ex1);          // sigmoid(-gate)
        float z = 1.0f - a;                                   // sigmoid(gate)
        float ex2 = __builtin_amdgcn_exp2f(-hid * LOG2E);     // exp(-hid)
        float gn = __builtin_amdgcn_rcpf(1.0f + ex2);         // sigmoid(hid)
        float g = (hid >= 0.0f) ? (hid + 0.5f) : gn;
        float bb = z * g;
        int row = 64 * wr + 16 * m + 4 * kg + r;
        pk[(size_t)(m0 + row) * ND + n0 + ch] =
            ((uint32_t)f2bf(bb) << 16) | (uint32_t)f2bf(a);
        Bs = fmaf(a, Bs, bb);   // ordered: r ascending
        As *= a;
      }
      Am[m] = As; Bm[m] = Bs;
    }
    // ordered affine all-reduce across kg (4-row segments within 16-row groups)
#pragma unroll
    for (int m = 0; m < 4; ++m) {
      float pA_ = __shfl_xor(Am[m], 16);
      float pB_ = __shfl_xor(Bm[m], 16);
      Bm[m] = (kg & 1) ? fmaf(Am[m], pB_, Bm[m]) : fmaf(pA_, Bm[m], pB_);
      Am[m] *= pA_;
      pA_ = __shfl_xor(Am[m], 32);
      pB_ = __shfl_xor(Bm[m], 32);
      Bm[m] = (kg & 2) ? fmaf(Am[m], pB_, Bm[m]) : fmaf(pA_, Bm[m], pB_);
      Am[m] *= pA_;
    }
    // serial over 16-row groups (ascending)
    float As = Am[0], Bs = Bm[0];
#pragma unroll
    for (int m = 1; m < 4; ++m) { Bs = fmaf(Am[m], Bs, Bm[m]); As *= Am[m]; }
    A64[n] = As; B64[n] = Bs;
  }
  // cross-wr combine (rows 0-63 then 64-127) via 512B LDS
  if (wr == 0 && kg == 0) {
#pragma unroll
    for (int n = 0; n < 2; ++n) {
      int ch = wc * 32 + n * 16 + fr;
      aggL[ch * 2] = A64[n];
      aggL[ch * 2 + 1] = B64[n];
    }
  }
  __syncthreads();
  if (wr == 1 && kg == 0) {
#pragma unroll
    for (int n = 0; n < 2; ++n) {
      int ch = wc * 32 + n * 16 + fr;
      float A0 = aggL[ch * 2], B0 = aggL[ch * 2 + 1];
      size_t o = (size_t)mblk * ND + n0 + ch;    // mblk == global chunk index
      aggA[o] = A0 * A64[n];
      aggB[o] = fmaf(A64[n], B0, B64[n]);
    }
  }
}

// ---------------- scan pass2: prefix + rescan, write out f32 ----------------
__global__ __launch_bounds__(256) void scan_pass2(const uint32_t* __restrict__ pk,
                                                  const float* __restrict__ aggA,
                                                  const float* __restrict__ aggB,
                                                  float* __restrict__ out,
                                                  float* __restrict__ nextp) {
  int bid = blockIdx.x;
  int b = bid >> 6;
  int c = bid & 63;
  int d2 = threadIdx.x;        // channel-pair 0..255

  float h0 = 0.0f, h1 = 0.0f;
  for (int cc = 0; cc < c; ++cc) {
    int o = (b * 64 + cc) * ND + d2 * 2;
    float2 Aa = *reinterpret_cast<const float2*>(&aggA[o]);
    float2 Bb = *reinterpret_cast<const float2*>(&aggB[o]);
    h0 = fmaf(Aa.x, h0, Bb.x);
    h1 = fmaf(Aa.y, h1, Bb.y);
  }
  size_t base = (size_t)(b * NS + c * 128) * ND + d2 * 2;
#pragma unroll 4
  for (int t = 0; t < 128; ++t) {
    size_t idx = base + (size_t)t * ND;
    uint2 v = *reinterpret_cast<const uint2*>(pk + idx);
    float a0 = __uint_as_float(v.x << 16);
    float b0 = __uint_as_float(v.x & 0xffff0000u);
    float a1 = __uint_as_float(v.y << 16);
    float b1 = __uint_as_float(v.y & 0xffff0000u);
    h0 = fmaf(a0, h0, b0);
    h1 = fmaf(a1, h1, b1);
    *reinterpret_cast<float2*>(&out[idx]) = make_float2(h0, h1);
  }
  if (c == 63) {
    *reinterpret_cast<float2*>(&nextp[b * ND + d2 * 2]) = make_float2(h0, h1);
  }
}

// ---------------- launcher ----------------
extern "C" void kernel_launch(void* const* d_in, const int* in_sizes, int n_in,
                              void* d_out, int out_size, void* d_ws, size_t ws_size,
                              hipStream_t stream) {
  const float* x = (const float*)d_in[0];   // (8, 8192, 512) f32
  const float* W = (const float*)d_in[1];   // (1024, 512) f32
  float* out = (float*)d_out;               // 33554432 + 4096 f32

  char* ws = (char*)d_ws;
  uint32_t* pk = (uint32_t*)ws;                                            // 128 MB
  unsigned short* wbf = (unsigned short*)(ws + (size_t)128 * 1024 * 1024); // 1 MB
  float* aggA = (float*)(ws + (size_t)129 * 1024 * 1024);                  // 1 MB
  float* aggB = (float*)(ws + (size_t)130 * 1024 * 1024);                  // 1 MB
  float* nextp = out + (size_t)NM * ND;

  cvt_bf16<<<256, 256, 0, stream>>>(W, wbf, (1024 * NK) / 8);
  gemm_ab<<<4096, 256, 0, stream>>>(x, wbf, pk, aggA, aggB);
  scan_pass2<<<512, 256, 0, stream>>>(pk, aggA, aggB, out, nextp);
}

// Round 17
// 236.823 us; speedup vs baseline: 1.7696x; 1.1241x over previous
//
#include <hip/hip_runtime.h>
#include <hip/hip_bf16.h>
#include <stdint.h>

typedef float f32x4 __attribute__((ext_vector_type(4)));
typedef __bf16 bf16x8 __attribute__((ext_vector_type(8)));
typedef unsigned short ushort8 __attribute__((ext_vector_type(8)));

#define NB 8
#define NS 8192
#define ND 512
#define NM (NB * NS)      // 65536 rows
#define NK 512            // reduction dim

// ---------------- f32 -> bf16 (RNE) ----------------
__device__ __forceinline__ unsigned short f2bf(float f) {
  unsigned u = __float_as_uint(f);
  u += 0x7FFFu + ((u >> 16) & 1u);
  return (unsigned short)(u >> 16);
}

__global__ __launch_bounds__(256) void cvt_bf16(const float* __restrict__ src,
                                                unsigned short* __restrict__ dst,
                                                int n8) {
  int i = blockIdx.x * 256 + threadIdx.x;
  if (i >= n8) return;
  const float4* s = reinterpret_cast<const float4*>(src + (size_t)i * 8);
  float4 v0 = s[0], v1 = s[1];
  ushort8 o;
  o[0] = f2bf(v0.x); o[1] = f2bf(v0.y); o[2] = f2bf(v0.z); o[3] = f2bf(v0.w);
  o[4] = f2bf(v1.x); o[5] = f2bf(v1.y); o[6] = f2bf(v1.z); o[7] = f2bf(v1.w);
  *reinterpret_cast<ushort8*>(dst + (size_t)i * 8) = o;
}

// ---------------- 256x64ch GEMM, m201-skeleton 8-phase, ring-3, counted vmcnt ----
// Block: 256 seq rows (= 2 scan chunks) x 64 channels (128 W-rows mixed so
// hid/gat pair in-thread). 8 waves (wr=w>>1 in 0..3: 64-row quarter; wc=w&1).
// Ring-3 kt-buffers (48KB each: A 32KB | B 16KB), BK=64, 2 phases/kt:
//   PH: {8 ds_read frags, 3 stage loads of kt+2, BAR, lgkmcnt(0)+SB,
//        setprio(1), 16 MFMA, setprio(0), [vmcnt(6)+SB at kt end], BAR}
// vmcnt law (FIFO): at end of kt, outstanding = kt+1's 6 + kt+2's 6; vmcnt(6)
// retires kt+1's (needed next), leaves kt+2's in flight. NEVER 0 until tail.
// Overwrite safety: buf s=(kt+2)%3 last read in kt-1 (lgkm0 before kt-1's final
// BAR); kt's stages issue after that BAR. Data-ready: buf c staged in kt-2,
// retired by kt-1-end vmcnt(6), published by the following BAR.
// Swizzles: R11's proven conflict-free (kk*2+kg*16)^((row&7)<<4) on 128B rows.
// Epilogue: in-reg a/b + packed pk + per-128-row-chunk aggregates (wr-pair
// combine via 1KB aggL).
__global__ __launch_bounds__(512) void gemm_ab(const unsigned short* __restrict__ xb,
                                               const unsigned short* __restrict__ wb,
                                               uint32_t* __restrict__ pk,
                                               float* __restrict__ aggA,
                                               float* __restrict__ aggB) {
  __shared__ __align__(16) char lds[3 * 49152];   // 144KB: 3 x (A 32KB | B 16KB)
  __shared__ float aggL[256];                     // 2 chunk-pairs x 64 ch x (A,B)

  const int tid = threadIdx.x;
  const int w = tid >> 6;          // 0..7
  const int lane = tid & 63;
  const int wr = w >> 1;           // 0..3 : 64-row quarter
  const int wc = w & 1;            // 32-ch half
  // T1 bijective XCD swizzle: 2048 blocks = 256 mblk x 8 nblk
  const int orig = blockIdx.x;
  const int wg = (orig & 7) * 256 + (orig >> 3);
  const int mblk = wg >> 3;
  const int nblk = wg & 7;
  const int m0 = mblk * 256;
  const int n0 = nblk * 64;

  const int lrow = lane >> 3;                    // 0..7
  const int lcol = (((lane & 7) ^ lrow) * 8);    // pre-swizzled source col (bf16)

  // staging sources: A 4 loads/thread (256 rows), B 2 loads/thread (128 W-rows)
  const unsigned short* pA[4];
#pragma unroll
  for (int g = 0; g < 4; ++g) {
    int row = g * 64 + w * 8 + lrow;
    pA[g] = xb + (size_t)(m0 + row) * NK + lcol;
  }
  const unsigned short* pB[2];
#pragma unroll
  for (int g = 0; g < 2; ++g) {
    int row = g * 64 + w * 8 + lrow;
    int e = (row < 64) ? (n0 + row) : (448 + n0 + row);  // hidden | gate W-rows
    pB[g] = wb + (size_t)e * NK + lcol;
  }

  const int fr = lane & 15;
  const int kg = lane >> 4;

  f32x4 acc[4][4];
#pragma unroll
  for (int i = 0; i < 4; ++i)
#pragma unroll
    for (int j = 0; j < 4; ++j) acc[i][j] = (f32x4)0.0f;

  bf16x8 af[4], bfr[4];

#define GLD(SRC, DSTOFF)                                                      \
  __builtin_amdgcn_global_load_lds(                                           \
      (const __attribute__((address_space(1))) void*)(SRC),                   \
      (__attribute__((address_space(3))) void*)(lds + (DSTOFF)), 16, 0, 0)

// first 3 staging loads of tile KT into buf S (A groups 0-2)
#define STG1(S, KT)                                                           \
  {                                                                           \
    GLD(pA[0] + (KT) * 64, (S) * 49152 + (0 * 8 + w) * 1024);                 \
    GLD(pA[1] + (KT) * 64, (S) * 49152 + (1 * 8 + w) * 1024);                 \
    GLD(pA[2] + (KT) * 64, (S) * 49152 + (2 * 8 + w) * 1024);                 \
  }
// last 3 staging loads (A group 3, B groups 0-1)
#define STG2(S, KT)                                                           \
  {                                                                           \
    GLD(pA[3] + (KT) * 64, (S) * 49152 + (3 * 8 + w) * 1024);                 \
    GLD(pB[0] + (KT) * 64, (S) * 49152 + 32768 + (0 * 8 + w) * 1024);         \
    GLD(pB[1] + (KT) * 64, (S) * 49152 + 32768 + (1 * 8 + w) * 1024);         \
  }

#define READF(C, KK)                                                          \
  {                                                                           \
    const char* ldsA_ = lds + (C) * 49152;                                    \
    const char* ldsB_ = ldsA_ + 32768;                                        \
    _Pragma("unroll")                                                         \
    for (int i = 0; i < 4; ++i) {                                             \
      int rowA = wr * 64 + i * 16 + fr;                                       \
      int sa = ((KK) * 2 + kg * 16) ^ ((rowA & 7) << 4);                      \
      af[i] = *reinterpret_cast<const bf16x8*>(ldsA_ + rowA * 128 + sa);      \
      int rowB = ((i < 2) ? (wc * 32 + i * 16) : (64 + wc * 32 + (i - 2) * 16)) + fr; \
      int sb = ((KK) * 2 + kg * 16) ^ ((rowB & 7) << 4);                      \
      bfr[i] = *reinterpret_cast<const bf16x8*>(ldsB_ + rowB * 128 + sb);     \
    }                                                                         \
  }

#define MFMA16()                                                              \
  {                                                                           \
    _Pragma("unroll")                                                         \
    for (int i = 0; i < 4; ++i)                                               \
      _Pragma("unroll")                                                       \
      for (int j = 0; j < 4; ++j)                                             \
        acc[i][j] = __builtin_amdgcn_mfma_f32_16x16x32_bf16(af[i], bfr[j],    \
                                                            acc[i][j], 0, 0, 0); \
  }

#define BAR() __builtin_amdgcn_s_barrier()
#define SB0() __builtin_amdgcn_sched_barrier(0)
#define LGKM0() asm volatile("s_waitcnt lgkmcnt(0)" ::: "memory")
#define VMC(N) asm volatile("s_waitcnt vmcnt(" #N ")" ::: "memory")

// one kt: C=kt%3, S=(kt+2)%3; DO=1 -> stage kt+2; WMODE: 1 -> vmcnt(6), 2 -> vmcnt(0), 0 -> none
#define ITER(KT, C, S, DO, WMODE)                                             \
  {                                                                           \
    READF(C, 0);                                                              \
    if (DO) STG1(S, (KT) + 2);                                                \
    BAR(); LGKM0(); SB0();                                                    \
    __builtin_amdgcn_s_setprio(1); MFMA16(); __builtin_amdgcn_s_setprio(0);   \
    BAR();                                                                    \
    READF(C, 32);                                                             \
    if (DO) STG2(S, (KT) + 2);                                                \
    BAR(); LGKM0(); SB0();                                                    \
    __builtin_amdgcn_s_setprio(1); MFMA16(); __builtin_amdgcn_s_setprio(0);   \
    if (WMODE == 1) { VMC(6); SB0(); }                                        \
    if (WMODE == 2) { VMC(0); SB0(); }                                        \
    BAR();                                                                    \
  }

  // prologue: kt0 -> buf0, kt1 -> buf1 (12 loads); wait kt0's 6, publish
  STG1(0, 0); STG2(0, 0);
  STG1(1, 1); STG2(1, 1);
  VMC(6); SB0();
  BAR();

  ITER(0, 0, 2, 1, 1);
  ITER(1, 1, 0, 1, 1);
  ITER(2, 2, 1, 1, 1);
  ITER(3, 0, 2, 1, 1);
  ITER(4, 1, 0, 1, 1);
  ITER(5, 2, 1, 1, 1);   // stages kt7; end: kt6 retired, kt7's 6 in flight
  ITER(6, 0, 2, 0, 2);   // no stage; end: vmcnt(0) -> kt7 ready
  ITER(7, 1, 0, 0, 0);   // last

#undef ITER
#undef GLD
#undef STG1
#undef STG2
#undef READF
#undef MFMA16
#undef BAR
#undef SB0
#undef LGKM0
#undef VMC

  // ---------------- epilogue: in-reg a/b + per-chunk aggregates ----------------
  const float LOG2E = 1.44269504f;
  float A64[2], B64[2];
#pragma unroll
  for (int n = 0; n < 2; ++n) {
    const int ch = wc * 32 + n * 16 + fr;
    float Am[4], Bm[4];
#pragma unroll
    for (int m = 0; m < 4; ++m) {
      float As = 1.0f, Bs = 0.0f;
#pragma unroll
      for (int r = 0; r < 4; ++r) {
        float hid = acc[m][n][r];
        float gat = acc[m][n + 2][r];
        float ex1 = __builtin_amdgcn_exp2f(gat * LOG2E);      // exp(gat)
        float a = __builtin_amdgcn_rcpf(1.0f + ex1);          // sigmoid(-gate)
        float z = 1.0f - a;                                   // sigmoid(gate)
        float ex2 = __builtin_amdgcn_exp2f(-hid * LOG2E);     // exp(-hid)
        float gn = __builtin_amdgcn_rcpf(1.0f + ex2);         // sigmoid(hid)
        float g = (hid >= 0.0f) ? (hid + 0.5f) : gn;
        float bb = z * g;
        int row = wr * 64 + 16 * m + 4 * kg + r;
        pk[(size_t)(m0 + row) * ND + n0 + ch] =
            ((uint32_t)f2bf(bb) << 16) | (uint32_t)f2bf(a);
        Bs = fmaf(a, Bs, bb);   // ordered: r ascending
        As *= a;
      }
      Am[m] = As; Bm[m] = Bs;
    }
    // ordered affine all-reduce across kg (4-row segments within 16-row groups)
#pragma unroll
    for (int m = 0; m < 4; ++m) {
      float pA_ = __shfl_xor(Am[m], 16);
      float pB_ = __shfl_xor(Bm[m], 16);
      Bm[m] = (kg & 1) ? fmaf(Am[m], pB_, Bm[m]) : fmaf(pA_, Bm[m], pB_);
      Am[m] *= pA_;
      pA_ = __shfl_xor(Am[m], 32);
      pB_ = __shfl_xor(Bm[m], 32);
      Bm[m] = (kg & 2) ? fmaf(Am[m], pB_, Bm[m]) : fmaf(pA_, Bm[m], pB_);
      Am[m] *= pA_;
    }
    // serial over the 4 16-row groups (ascending) -> this wave's 64-row aggregate
    float As = Am[0], Bs = Bm[0];
#pragma unroll
    for (int m = 1; m < 4; ++m) { Bs = fmaf(Am[m], Bs, Bm[m]); As *= Am[m]; }
    A64[n] = As; B64[n] = Bs;
  }
  // wr-pair combine: even wr = rows 0-63 of its 128-row chunk, odd wr = rows 64-127
  if ((wr & 1) == 0 && kg == 0) {
#pragma unroll
    for (int n = 0; n < 2; ++n) {
      int ch = wc * 32 + n * 16 + fr;
      aggL[(wr >> 1) * 128 + ch * 2] = A64[n];
      aggL[(wr >> 1) * 128 + ch * 2 + 1] = B64[n];
    }
  }
  __syncthreads();
  if ((wr & 1) == 1 && kg == 0) {
#pragma unroll
    for (int n = 0; n < 2; ++n) {
      int ch = wc * 32 + n * 16 + fr;
      float A0 = aggL[(wr >> 1) * 128 + ch * 2];
      float B0 = aggL[(wr >> 1) * 128 + ch * 2 + 1];
      size_t o = (size_t)(mblk * 2 + (wr >> 1)) * ND + n0 + ch;  // global chunk idx
      aggA[o] = A0 * A64[n];
      aggB[o] = fmaf(A64[n], B0, B64[n]);
    }
  }
}

// ---------------- scan pass2: prefix + rescan, write out f32 ----------------
__global__ __launch_bounds__(256) void scan_pass2(const uint32_t* __restrict__ pk,
                                                  const float* __restrict__ aggA,
                                                  const float* __restrict__ aggB,
                                                  float* __restrict__ out,
                                                  float* __restrict__ nextp) {
  int bid = blockIdx.x;
  int b = bid >> 6;
  int c = bid & 63;
  int d2 = threadIdx.x;        // channel-pair 0..255

  float h0 = 0.0f, h1 = 0.0f;
  for (int cc = 0; cc < c; ++cc) {
    int o = (b * 64 + cc) * ND + d2 * 2;
    float2 Aa = *reinterpret_cast<const float2*>(&aggA[o]);
    float2 Bb = *reinterpret_cast<const float2*>(&aggB[o]);
    h0 = fmaf(Aa.x, h0, Bb.x);
    h1 = fmaf(Aa.y, h1, Bb.y);
  }
  size_t base = (size_t)(b * NS + c * 128) * ND + d2 * 2;
#pragma unroll 4
  for (int t = 0; t < 128; ++t) {
    size_t idx = base + (size_t)t * ND;
    uint2 v = *reinterpret_cast<const uint2*>(pk + idx);
    float a0 = __uint_as_float(v.x << 16);
    float b0 = __uint_as_float(v.x & 0xffff0000u);
    float a1 = __uint_as_float(v.y << 16);
    float b1 = __uint_as_float(v.y & 0xffff0000u);
    h0 = fmaf(a0, h0, b0);
    h1 = fmaf(a1, h1, b1);
    *reinterpret_cast<float2*>(&out[idx]) = make_float2(h0, h1);
  }
  if (c == 63) {
    *reinterpret_cast<float2*>(&nextp[b * ND + d2 * 2]) = make_float2(h0, h1);
  }
}

// ---------------- launcher ----------------
extern "C" void kernel_launch(void* const* d_in, const int* in_sizes, int n_in,
                              void* d_out, int out_size, void* d_ws, size_t ws_size,
                              hipStream_t stream) {
  const float* x = (const float*)d_in[0];   // (8, 8192, 512) f32
  const float* W = (const float*)d_in[1];   // (1024, 512) f32
  float* out = (float*)d_out;               // 33554432 + 4096 f32

  char* ws = (char*)d_ws;
  unsigned short* xb  = (unsigned short*)ws;                              // 64 MB
  unsigned short* wbf = (unsigned short*)(ws + (size_t)64 * 1024 * 1024); // 1 MB
  uint32_t* pk = (uint32_t*)(ws + (size_t)65 * 1024 * 1024);              // 128 MB
  float* aggA = (float*)(ws + (size_t)193 * 1024 * 1024);                 // 1 MB
  float* aggB = (float*)(ws + (size_t)194 * 1024 * 1024);                 // 1 MB
  float* nextp = out + (size_t)NM * ND;

  cvt_bf16<<<16384, 256, 0, stream>>>(x, xb, (NM * NK) / 8);
  cvt_bf16<<<256, 256, 0, stream>>>(W, wbf, (1024 * NK) / 8);
  gemm_ab<<<2048, 512, 0, stream>>>(xb, wbf, pk, aggA, aggB);
  scan_pass2<<<512, 256, 0, stream>>>(pk, aggA, aggB, out, nextp);
}

// Round 19
// 225.136 us; speedup vs baseline: 1.8615x; 1.0519x over previous
//
#include <hip/hip_runtime.h>
#include <hip/hip_bf16.h>
#include <stdint.h>

typedef float f32x4 __attribute__((ext_vector_type(4)));
typedef __bf16 bf16x8 __attribute__((ext_vector_type(8)));
typedef unsigned short ushort8 __attribute__((ext_vector_type(8)));

#define NB 8
#define NS 8192
#define ND 512
#define NM (NB * NS)      // 65536 rows
#define NK 512            // reduction dim

// ---------------- f32 -> bf16 (RNE) ----------------
__device__ __forceinline__ unsigned short f2bf(float f) {
  unsigned u = __float_as_uint(f);
  u += 0x7FFFu + ((u >> 16) & 1u);
  return (unsigned short)(u >> 16);
}

__global__ __launch_bounds__(256) void cvt_bf16(const float* __restrict__ src,
                                                unsigned short* __restrict__ dst,
                                                int n8) {
  int i = blockIdx.x * 256 + threadIdx.x;
  if (i >= n8) return;
  const float4* s = reinterpret_cast<const float4*>(src + (size_t)i * 8);
  float4 v0 = s[0], v1 = s[1];
  ushort8 o;
  o[0] = f2bf(v0.x); o[1] = f2bf(v0.y); o[2] = f2bf(v0.z); o[3] = f2bf(v0.w);
  o[4] = f2bf(v1.x); o[5] = f2bf(v1.y); o[6] = f2bf(v1.z); o[7] = f2bf(v1.w);
  *reinterpret_cast<ushort8*>(dst + (size_t)i * 8) = o;
}

// ---------------- 256x128ch GEMM, 2-phase dbuf, in-register a/b epilogue -------
// Block: 256 seq rows (= 2 scan chunks) x 128 channels (B panel = 256 W-rows:
// 128 hidden + 128 gate). 8 waves = 2(wm: 128-row half = one chunk) x 4(wn:
// 32-ch group). Mixed B-frags: n<2 -> hidden W-row wn*32+n*16, n>=2 -> gate
// W-row 128+wn*32+(n-2)*16, so hid=acc[m][n], gat=acc[m][n+2] pair in-thread.
// Per wave per kt: 24 ds_read_b128 + 64 MFMA (5.3:1 per phase vs R11's 2:1 --
// the m201 tile-ratio lever). K-loop sync = R6/R11's verified 2-phase:
// stage(next) FIRST, compute(cur), ONE __syncthreads. LDS 128KB (2 x (A 32KB |
// B 32KB)), R11's proven zero-conflict swizzle everywhere. T1 XCD grid swizzle.
// Epilogue: pure-register a/b + packed pk + WAVE-LOCAL chunk aggregates (one
// wave owns a full 128-row chunk -> no cross-wave combine).
__global__ __launch_bounds__(512, 2) void gemm_ab(const unsigned short* __restrict__ xb,
                                                  const unsigned short* __restrict__ wb,
                                                  uint32_t* __restrict__ pk,
                                                  float* __restrict__ aggA,
                                                  float* __restrict__ aggB) {
  __shared__ __align__(16) char lds[2 * 65536];   // 128KB: buf{0,1} x (A 32KB | B 32KB)

  const int tid = threadIdx.x;
  const int w = tid >> 6;          // 0..7
  const int lane = tid & 63;
  const int wm = w >> 2;           // 0..1 : 128-row half (= scan chunk)
  const int wn = w & 3;            // 0..3 : 32-channel group
  // T1 bijective XCD swizzle: 1024 blocks = 256 mblk x 4 nblk
  const int orig = blockIdx.x;
  const int wg = (orig & 7) * 128 + (orig >> 3);
  const int mblk = wg >> 2;
  const int nblk = wg & 3;
  const int m0 = mblk * 256;
  const int n0 = nblk * 128;       // 128 channels per block

  const int lrow = lane >> 3;                    // 0..7
  const int lcol = (((lane & 7) ^ lrow) * 8);    // pre-swizzled source col (bf16)

  // staging sources: A 4 loads/thread (256 rows), B 4 loads/thread (256 W-rows)
  const unsigned short* pA[4];
  const unsigned short* pB[4];
#pragma unroll
  for (int g = 0; g < 4; ++g) {
    int row = g * 64 + w * 8 + lrow;
    pA[g] = xb + (size_t)(m0 + row) * NK + lcol;
    int e = (row < 128) ? (n0 + row) : (384 + n0 + row);  // hidden | gate W-rows
    pB[g] = wb + (size_t)e * NK + lcol;
  }

  auto stage = [&](int buf, int kt) {
    char* base = lds + buf * 65536;
    const int ko = kt << 6;
#pragma unroll
    for (int g = 0; g < 4; ++g) {
      __builtin_amdgcn_global_load_lds(
          (const __attribute__((address_space(1))) void*)(pA[g] + ko),
          (__attribute__((address_space(3))) void*)(base + g * 8192 + w * 1024),
          16, 0, 0);
      __builtin_amdgcn_global_load_lds(
          (const __attribute__((address_space(1))) void*)(pB[g] + ko),
          (__attribute__((address_space(3))) void*)(base + 32768 + g * 8192 + w * 1024),
          16, 0, 0);
    }
  };

  const int fr = lane & 15;
  const int kg = lane >> 4;

  f32x4 acc[8][4];
#pragma unroll
  for (int i = 0; i < 8; ++i)
#pragma unroll
    for (int j = 0; j < 4; ++j) acc[i][j] = (f32x4)0.0f;

  stage(0, 0);
  __syncthreads();

#pragma unroll 1
  for (int kt = 0; kt < 8; ++kt) {
    const int cur = kt & 1;
    if (kt < 7) stage(cur ^ 1, kt + 1);   // issue next-tile loads FIRST

    const char* ldsA = lds + cur * 65536;
    const char* ldsB = ldsA + 32768;
#pragma unroll
    for (int kk = 0; kk < 64; kk += 32) {
      bf16x8 af[8], bfr[4];
#pragma unroll
      for (int i = 0; i < 8; ++i) {
        int rowA = wm * 128 + i * 16 + fr;
        int sa = (kk * 2 + kg * 16) ^ ((rowA & 7) << 4);
        af[i] = *reinterpret_cast<const bf16x8*>(ldsA + rowA * 128 + sa);
      }
#pragma unroll
      for (int n = 0; n < 4; ++n) {
        int rowB = ((n < 2) ? (wn * 32 + n * 16) : (128 + wn * 32 + (n - 2) * 16)) + fr;
        int sb = (kk * 2 + kg * 16) ^ ((rowB & 7) << 4);
        bfr[n] = *reinterpret_cast<const bf16x8*>(ldsB + rowB * 128 + sb);
      }
#pragma unroll
      for (int i = 0; i < 8; ++i)
#pragma unroll
        for (int j = 0; j < 4; ++j)
          acc[i][j] = __builtin_amdgcn_mfma_f32_16x16x32_bf16(af[i], bfr[j], acc[i][j], 0, 0, 0);
    }
    __syncthreads();   // one barrier per K-tile
  }

  // ---------------- epilogue: pure-register a/b + wave-local chunk aggregates ----
  const float LOG2E = 1.44269504f;
#pragma unroll
  for (int n = 0; n < 2; ++n) {
    const int ch = wn * 32 + n * 16 + fr;
    float Am[8], Bm[8];
#pragma unroll
    for (int m = 0; m < 8; ++m) {
      float As = 1.0f, Bs = 0.0f;
#pragma unroll
      for (int r = 0; r < 4; ++r) {
        float hid = acc[m][n][r];
        float gat = acc[m][n + 2][r];
        float ex1 = __builtin_amdgcn_exp2f(gat * LOG2E);      // exp(gat)
        float a = __builtin_amdgcn_rcpf(1.0f + ex1);          // sigmoid(-gate)
        float z = 1.0f - a;                                   // sigmoid(gate)
        float ex2 = __builtin_amdgcn_exp2f(-hid * LOG2E);     // exp(-hid)
        float gn = __builtin_amdgcn_rcpf(1.0f + ex2);         // sigmoid(hid)
        float g = (hid >= 0.0f) ? (hid + 0.5f) : gn;
        float bb = z * g;
        int row = wm * 128 + 16 * m + 4 * kg + r;
        pk[(size_t)(m0 + row) * ND + n0 + ch] =
            ((uint32_t)f2bf(bb) << 16) | (uint32_t)f2bf(a);
        Bs = fmaf(a, Bs, bb);   // ordered: r ascending
        As *= a;
      }
      Am[m] = As; Bm[m] = Bs;
    }
    // ordered affine all-reduce across kg (4-row segments within 16-row groups)
#pragma unroll
    for (int m = 0; m < 8; ++m) {
      float pA_ = __shfl_xor(Am[m], 16);
      float pB_ = __shfl_xor(Bm[m], 16);
      Bm[m] = (kg & 1) ? fmaf(Am[m], pB_, Bm[m]) : fmaf(pA_, Bm[m], pB_);
      Am[m] *= pA_;
      pA_ = __shfl_xor(Am[m], 32);
      pB_ = __shfl_xor(Bm[m], 32);
      Bm[m] = (kg & 2) ? fmaf(Am[m], pB_, Bm[m]) : fmaf(pA_, Bm[m], pB_);
      Am[m] *= pA_;
    }
    // serial over the 8 16-row groups (ascending) -> full 128-row chunk aggregate
    float As = Am[0], Bs = Bm[0];
#pragma unroll
    for (int m = 1; m < 8; ++m) { Bs = fmaf(Am[m], Bs, Bm[m]); As *= Am[m]; }
    if (kg == 0) {
      size_t o = (size_t)(mblk * 2 + wm) * ND + n0 + ch;   // global chunk index
      aggA[o] = As;
      aggB[o] = Bs;
    }
  }
}

// ---------------- scan pass2: prefix + rescan, write out f32 ----------------
__global__ __launch_bounds__(256) void scan_pass2(const uint32_t* __restrict__ pk,
                                                  const float* __restrict__ aggA,
                                                  const float* __restrict__ aggB,
                                                  float* __restrict__ out,
                                                  float* __restrict__ nextp) {
  int bid = blockIdx.x;
  int b = bid >> 6;
  int c = bid & 63;
  int d2 = threadIdx.x;        // channel-pair 0..255

  float h0 = 0.0f, h1 = 0.0f;
  for (int cc = 0; cc < c; ++cc) {
    int o = (b * 64 + cc) * ND + d2 * 2;
    float2 Aa = *reinterpret_cast<const float2*>(&aggA[o]);
    float2 Bb = *reinterpret_cast<const float2*>(&aggB[o]);
    h0 = fmaf(Aa.x, h0, Bb.x);
    h1 = fmaf(Aa.y, h1, Bb.y);
  }
  size_t base = (size_t)(b * NS + c * 128) * ND + d2 * 2;
#pragma unroll 4
  for (int t = 0; t < 128; ++t) {
    size_t idx = base + (size_t)t * ND;
    uint2 v = *reinterpret_cast<const uint2*>(pk + idx);
    float a0 = __uint_as_float(v.x << 16);
    float b0 = __uint_as_float(v.x & 0xffff0000u);
    float a1 = __uint_as_float(v.y << 16);
    float b1 = __uint_as_float(v.y & 0xffff0000u);
    h0 = fmaf(a0, h0, b0);
    h1 = fmaf(a1, h1, b1);
    *reinterpret_cast<float2*>(&out[idx]) = make_float2(h0, h1);
  }
  if (c == 63) {
    *reinterpret_cast<float2*>(&nextp[b * ND + d2 * 2]) = make_float2(h0, h1);
  }
}

// ---------------- launcher ----------------
extern "C" void kernel_launch(void* const* d_in, const int* in_sizes, int n_in,
                              void* d_out, int out_size, void* d_ws, size_t ws_size,
                              hipStream_t stream) {
  const float* x = (const float*)d_in[0];   // (8, 8192, 512) f32
  const float* W = (const float*)d_in[1];   // (1024, 512) f32
  float* out = (float*)d_out;               // 33554432 + 4096 f32

  char* ws = (char*)d_ws;
  unsigned short* xb  = (unsigned short*)ws;                              // 64 MB
  unsigned short* wbf = (unsigned short*)(ws + (size_t)64 * 1024 * 1024); // 1 MB
  uint32_t* pk = (uint32_t*)(ws + (size_t)65 * 1024 * 1024);              // 128 MB
  float* aggA = (float*)(ws + (size_t)193 * 1024 * 1024);                 // 1 MB
  float* aggB = (float*)(ws + (size_t)194 * 1024 * 1024);                 // 1 MB
  float* nextp = out + (size_t)NM * ND;

  cvt_bf16<<<16384, 256, 0, stream>>>(x, xb, (NM * NK) / 8);
  cvt_bf16<<<256, 256, 0, stream>>>(W, wbf, (1024 * NK) / 8);
  gemm_ab<<<1024, 512, 0, stream>>>(xb, wbf, pk, aggA, aggB);
  scan_pass2<<<512, 256, 0, stream>>>(pk, aggA, aggB, out, nextp);
}